// Round 3
// baseline (299.694 us; speedup 1.0000x reference)
//
#include <hip/hip_runtime.h>
#include <math.h>

// ---------------------------------------------------------------------------
// out = DHT2_128( crop_center_128( DHT2_256(x) ) ), x: (512, 256, 256) fp32.
// bf16 MFMA throughout. Uses the Hartley symmetry Q[n][v] = P[n][(N-v)%N] so
// only P columns are computed; the Q operand is read from the mirrored row.
//
// ws layout (bf16 elements):
//   W1t [144][256] @ 0      : cas(2pi (64+c) m / 256)   (c 0..128 used)
//   W2  [128][512] @ 36864  : k<256 -> cos(2pi (64+u) k /256); k>=256 -> sin
//   W3t [128][128] @ 102400 : cas(2pi c m / 128)
//   W4  [128][256] @ 118784 : k<128 -> cos(2pi u k /128); k>=128 -> sin
// ---------------------------------------------------------------------------

typedef __attribute__((ext_vector_type(8))) short bfrag;   // 8 bf16
typedef __attribute__((ext_vector_type(4))) float ffrag;   // 4 fp32 acc

#define PI2_256 0.0245436926061702597f
#define PI2_128 0.0490873852123405194f

__device__ __forceinline__ unsigned short f2bf(float f) {
    union { float f; unsigned int u; } v; v.f = f;
    unsigned int r = v.u + 0x7fffu + ((v.u >> 16) & 1u);
    return (unsigned short)(r >> 16);
}

__device__ __forceinline__ bfrag pack8(float4 a, float4 b) {
    bfrag r;
    r[0] = (short)f2bf(a.x); r[1] = (short)f2bf(a.y);
    r[2] = (short)f2bf(a.z); r[3] = (short)f2bf(a.w);
    r[4] = (short)f2bf(b.x); r[5] = (short)f2bf(b.y);
    r[6] = (short)f2bf(b.z); r[7] = (short)f2bf(b.w);
    return r;
}

// ---------------------------------------------------------------------------
__global__ __launch_bounds__(256) void gen_tables(unsigned short* __restrict__ ws)
{
    const int id = blockIdx.x * 256 + threadIdx.x;   // 65536 threads
    // W2: 65536 elems
    {
        const int u = id >> 9, k = id & 511;
        const int up = 64 + u;
        float s, c, val;
        if (k < 256) { sincosf((float)((up * k) & 255) * PI2_256, &s, &c); val = c; }
        else         { sincosf((float)((up * (k - 256)) & 255) * PI2_256, &s, &c); val = s; }
        ws[36864 + id] = f2bf(val);
    }
    if (id < 36864) {   // W1t
        const int c = id >> 8, m = id & 255;
        const int idx = ((64 + c) * m) & 255;
        float s, cc; sincosf((float)idx * PI2_256, &s, &cc);
        ws[id] = f2bf(cc + s);
    }
    if (id < 16384) {   // W3t
        const int c = id >> 7, m = id & 127;
        const int idx = (c * m) & 127;
        float s, cc; sincosf((float)idx * PI2_128, &s, &cc);
        ws[102400 + id] = f2bf(cc + s);
    }
    if (id < 32768) {   // W4
        const int u = id >> 8, k = id & 255;
        float s, c, val;
        if (k < 128) { sincosf((float)((u * k) & 127) * PI2_128, &s, &c); val = c; }
        else         { sincosf((float)((u * (k - 128)) & 127) * PI2_128, &s, &c); val = s; }
        ws[118784 + id] = f2bf(val);
    }
}

// ---------------------------------------------------------------------------
// Stage 1: one block per image, 512 threads (8 waves), 66 KB LDS -> 2 blk/CU.
//   Phase A (2 row-passes): Pt[c][n] = sum_m X[n][m] W1t[c][m], c in [0,128]
//   Phase B: Dc[u][v] = sum_{k<256} W2[u][k] Pt[v][k]
//                     + sum_{k>=256} W2[u][k] Pt[128-v][k-256]
// ---------------------------------------------------------------------------
__global__ __launch_bounds__(512, 4) void stage1(const float* __restrict__ X,
                                                 const unsigned short* __restrict__ ws,
                                                 float* __restrict__ dc)
{
    __shared__ unsigned short Pt[129 * 256];   // 66,048 B, XOR-swizzled (granule 8 bf16)

    const int t  = threadIdx.x;
    const int w  = t >> 6;          // wave 0..7
    const int ln = t & 15;
    const int q  = (t & 63) >> 4;   // quad 0..3

    const float* __restrict__ Xi = X + (size_t)blockIdx.x * 65536;
    const unsigned short* __restrict__ W1 = ws;            // [144][256]
    const unsigned short* __restrict__ W2 = ws + 36864;    // [128][512]

    // ---- Phase A: two passes of 128 rows (8 waves x 16 rows) ----
#pragma unroll
    for (int rp = 0; rp < 2; ++rp) {
        const int base = rp * 128 + w * 16;
        ffrag acc[9];
#pragma unroll
        for (int nt = 0; nt < 9; ++nt) acc[nt] = (ffrag){0.f, 0.f, 0.f, 0.f};

        const float* __restrict__ xrow = Xi + (size_t)(base + ln) * 256;
#pragma unroll
        for (int kk = 0; kk < 8; ++kk) {
            const int k = kk * 32 + q * 8;
            const float4 x0 = *(const float4*)(xrow + k);
            const float4 x1 = *(const float4*)(xrow + k + 4);
            const bfrag A = pack8(x0, x1);
#pragma unroll
            for (int nt = 0; nt < 9; ++nt) {
                const bfrag B = *(const bfrag*)(W1 + (nt * 16 + ln) * 256 + k);
                acc[nt] = __builtin_amdgcn_mfma_f32_16x16x32_bf16(A, B, acc[nt], 0, 0, 0);
            }
        }
        const int n0 = base + 4 * q;
#pragma unroll
        for (int nt = 0; nt < 9; ++nt) {
            const int c = nt * 16 + ln;
            if (nt < 8 || ln == 0) {     // rows 0..128 only
                const unsigned int lo = (unsigned int)f2bf(acc[nt][0]) |
                                        ((unsigned int)f2bf(acc[nt][1]) << 16);
                const unsigned int hi = (unsigned int)f2bf(acc[nt][2]) |
                                        ((unsigned int)f2bf(acc[nt][3]) << 16);
                const int phys = c * 256 + (((n0 >> 3) ^ (c & 7)) << 3) + (n0 & 7);
                *(uint2*)&Pt[phys] = make_uint2(lo, hi);
            }
        }
    }
    __syncthreads();

    // ---- Phase B ----
    {
        ffrag acc[8];
#pragma unroll
        for (int nt = 0; nt < 8; ++nt) acc[nt] = (ffrag){0.f, 0.f, 0.f, 0.f};

        const int u0 = w * 16;
#pragma unroll
        for (int kk = 0; kk < 16; ++kk) {
            const int k = kk * 32 + q * 8;
            const bfrag A = *(const bfrag*)(W2 + (size_t)(u0 + ln) * 512 + k);
            const bool loK = (kk < 8);
#pragma unroll
            for (int nt = 0; nt < 8; ++nt) {
                const int v   = nt * 16 + ln;
                const int row = loK ? v : (128 - v);
                const int col = loK ? k : (k - 256);
                const int phys = row * 256 + (((col >> 3) ^ (row & 7)) << 3);
                const bfrag B = *(const bfrag*)&Pt[phys];
                acc[nt] = __builtin_amdgcn_mfma_f32_16x16x32_bf16(A, B, acc[nt], 0, 0, 0);
            }
        }
        float* __restrict__ D = dc + (size_t)blockIdx.x * 16384;
#pragma unroll
        for (int nt = 0; nt < 8; ++nt) {
#pragma unroll
            for (int r = 0; r < 4; ++r) {
                D[(u0 + 4 * q + r) * 128 + nt * 16 + ln] = acc[nt][r];
            }
        }
    }
}

// ---------------------------------------------------------------------------
// Stage 2: one block per image, 512 threads, 32 KB LDS. In-place on d_out:
// wave w only reads/writes rows [16w,16w+16) of its image, so no global race;
// the single barrier orders the LDS transpose.
//   A2: P2t[c][p] = sum_m Dc[p][m] W3t[c][m]
//   B2: out[u][v] = sum_{k<128} W4[u][k] P2t[v][k]
//                 + sum_{k>=128} W4[u][k] P2t[(128-v)&127][k-128]
// ---------------------------------------------------------------------------
__global__ __launch_bounds__(512, 4) void stage2(const unsigned short* __restrict__ ws,
                                                 float* __restrict__ io)
{
    __shared__ unsigned short P2t[128 * 128];   // 32 KiB swizzled

    const int t  = threadIdx.x;
    const int w  = t >> 6;
    const int ln = t & 15;
    const int q  = (t & 63) >> 4;

    float* __restrict__ G = io + (size_t)blockIdx.x * 16384;
    const unsigned short* __restrict__ W3 = ws + 102400;   // [128][128]
    const unsigned short* __restrict__ W4 = ws + 118784;   // [128][256]

    // ---- A2 ----
    {
        ffrag acc[8];
#pragma unroll
        for (int nt = 0; nt < 8; ++nt) acc[nt] = (ffrag){0.f, 0.f, 0.f, 0.f};

        const int p0 = w * 16;
        const float* __restrict__ drow = G + (size_t)(p0 + ln) * 128;
#pragma unroll
        for (int kk = 0; kk < 4; ++kk) {
            const int k = kk * 32 + q * 8;
            const float4 x0 = *(const float4*)(drow + k);
            const float4 x1 = *(const float4*)(drow + k + 4);
            const bfrag A = pack8(x0, x1);
#pragma unroll
            for (int nt = 0; nt < 8; ++nt) {
                const bfrag B = *(const bfrag*)(W3 + (nt * 16 + ln) * 128 + k);
                acc[nt] = __builtin_amdgcn_mfma_f32_16x16x32_bf16(A, B, acc[nt], 0, 0, 0);
            }
        }
        const int n0 = p0 + 4 * q;
#pragma unroll
        for (int nt = 0; nt < 8; ++nt) {
            const int c = nt * 16 + ln;
            const unsigned int lo = (unsigned int)f2bf(acc[nt][0]) |
                                    ((unsigned int)f2bf(acc[nt][1]) << 16);
            const unsigned int hi = (unsigned int)f2bf(acc[nt][2]) |
                                    ((unsigned int)f2bf(acc[nt][3]) << 16);
            const int phys = c * 128 + (((n0 >> 3) ^ (c & 7)) << 3) + (n0 & 7);
            *(uint2*)&P2t[phys] = make_uint2(lo, hi);
        }
    }
    __syncthreads();

    // ---- B2 ----
    {
        ffrag o[8];
#pragma unroll
        for (int nt = 0; nt < 8; ++nt) o[nt] = (ffrag){0.f, 0.f, 0.f, 0.f};

        const int u0 = w * 16;
#pragma unroll
        for (int kk = 0; kk < 8; ++kk) {
            const int k = kk * 32 + q * 8;
            const bfrag A = *(const bfrag*)(W4 + (size_t)(u0 + ln) * 256 + k);
            const bool loK = (kk < 4);
#pragma unroll
            for (int nt = 0; nt < 8; ++nt) {
                const int v   = nt * 16 + ln;
                const int row = loK ? v : ((128 - v) & 127);
                const int col = loK ? k : (k - 128);
                const int phys = row * 128 + (((col >> 3) ^ (row & 7)) << 3);
                const bfrag B = *(const bfrag*)&P2t[phys];
                o[nt] = __builtin_amdgcn_mfma_f32_16x16x32_bf16(A, B, o[nt], 0, 0, 0);
            }
        }
#pragma unroll
        for (int nt = 0; nt < 8; ++nt) {
#pragma unroll
            for (int r = 0; r < 4; ++r) {
                G[(u0 + 4 * q + r) * 128 + nt * 16 + ln] = o[nt][r];
            }
        }
    }
}

// ---------------------------------------------------------------------------
extern "C" void kernel_launch(void* const* d_in, const int* in_sizes, int n_in,
                              void* d_out, int out_size, void* d_ws, size_t ws_size,
                              hipStream_t stream)
{
    const float* x = (const float*)d_in[0];
    float* out = (float*)d_out;
    unsigned short* tw = (unsigned short*)d_ws;   // needs 303,104 bytes

    gen_tables<<<dim3(256), dim3(256), 0, stream>>>(tw);
    stage1<<<dim3(512), dim3(512), 0, stream>>>(x, tw, out);
    stage2<<<dim3(512), dim3(512), 0, stream>>>(tw, out);
}

// Round 4
// 292.766 us; speedup vs baseline: 1.0237x; 1.0237x over previous
//
#include <hip/hip_runtime.h>
#include <math.h>

// ---------------------------------------------------------------------------
// out = DHT2_128( crop_center_128( DHT2_256(x) ) ), x: (512, 256, 256) fp32.
// Single fused kernel per image (1024 thr). bf16 MFMA 16x16x32 for all four
// GEMMs. Hartley symmetry Q[v] = P[(N-v)%N] -> only P columns computed.
//
// ws (bf16): W1t[144][256]@0 : cas(2pi (64+c) m /256)
//            W2 [128][512]@36864 : k<256 cos(2pi(64+u)k/256), k>=256 sin
//            W3t[128][128]@102400: cas(2pi c m /128)
//            W4 [128][256]@118784: k<128 cos(2pi u k/128), k>=128 sin
//
// LDS (bf16 elems): PT region @0, 129 rows x stride 264 (34,056 el)
//                   XB region @34056: Xb 128 x 264 | later Dcb 128x136 @34056
//                   + P2t 128x136 @51464.  outS fp32 128 x stride 132 @byte 0.
// Padded strides (264/136 el -> 528/272 B == 4-bank shift/row) keep all b128
// fragment reads & uint2 writes bank-uniform. Total LDS 137,744 B.
// ---------------------------------------------------------------------------

typedef __attribute__((ext_vector_type(8))) short bfrag;
typedef __attribute__((ext_vector_type(4))) float ffrag;

#define PI2_256 0.0245436926061702597f
#define PI2_128 0.0490873852123405194f

constexpr int PT_E  = 0;        // stride 264, rows 0..128
constexpr int XB_E  = 34056;    // stride 264, rows 0..127
constexpr int DCB_E = 34056;    // stride 136, rows 0..127
constexpr int P2T_E = 51464;    // stride 136, rows 0..127

__device__ __forceinline__ unsigned short f2bf(float f) {
    union { float f; unsigned int u; } v; v.f = f;
    unsigned int r = v.u + 0x7fffu + ((v.u >> 16) & 1u);
    return (unsigned short)(r >> 16);
}

__device__ __forceinline__ uint2 pack4(float4 a) {
    uint2 r;
    r.x = (unsigned)f2bf(a.x) | ((unsigned)f2bf(a.y) << 16);
    r.y = (unsigned)f2bf(a.z) | ((unsigned)f2bf(a.w) << 16);
    return r;
}

// ---------------------------------------------------------------------------
__global__ __launch_bounds__(256) void gen_tables(unsigned short* __restrict__ ws)
{
    const int id = blockIdx.x * 256 + threadIdx.x;   // 65536 threads
    {
        const int u = id >> 9, k = id & 511;
        const int up = 64 + u;
        float s, c, val;
        if (k < 256) { sincosf((float)((up * k) & 255) * PI2_256, &s, &c); val = c; }
        else         { sincosf((float)((up * (k - 256)) & 255) * PI2_256, &s, &c); val = s; }
        ws[36864 + id] = f2bf(val);
    }
    if (id < 36864) {   // W1t
        const int c = id >> 8, m = id & 255;
        float s, cc; sincosf((float)(((64 + c) * m) & 255) * PI2_256, &s, &cc);
        ws[id] = f2bf(cc + s);
    }
    if (id < 16384) {   // W3t
        const int c = id >> 7, m = id & 127;
        float s, cc; sincosf((float)((c * m) & 127) * PI2_128, &s, &cc);
        ws[102400 + id] = f2bf(cc + s);
    }
    if (id < 32768) {   // W4
        const int u = id >> 8, k = id & 255;
        float s, c, val;
        if (k < 128) { sincosf((float)((u * k) & 127) * PI2_128, &s, &c); val = c; }
        else         { sincosf((float)((u * (k - 128)) & 127) * PI2_128, &s, &c); val = s; }
        ws[118784 + id] = f2bf(val);
    }
}

// ---------------------------------------------------------------------------
__device__ __forceinline__ void phaseA(unsigned short* sm, const unsigned short* W1,
                                       int pan, int w, int ln, int q)
{
    const int a   = w & 7;            // n-tile within panel
    const int ct0 = (w >> 3) * 4;     // c-tiles ct0..ct0+4 (overlap at ct=4 is benign dup)
    ffrag acc[5];
#pragma unroll
    for (int i = 0; i < 5; ++i) acc[i] = (ffrag){0.f, 0.f, 0.f, 0.f};

#pragma unroll
    for (int kk = 0; kk < 8; ++kk) {
        const int k = kk * 32 + q * 8;
        const bfrag A = *(const bfrag*)&sm[XB_E + (a * 16 + ln) * 264 + k];
#pragma unroll
        for (int i = 0; i < 5; ++i) {
            const bfrag B = *(const bfrag*)(W1 + ((ct0 + i) * 16 + ln) * 256 + k);
            acc[i] = __builtin_amdgcn_mfma_f32_16x16x32_bf16(A, B, acc[i], 0, 0, 0);
        }
    }
    const int nb = pan * 128 + a * 16 + 4 * q;
#pragma unroll
    for (int i = 0; i < 5; ++i) {
        const int cc = (ct0 + i) * 16 + ln;
        if (cc <= 128) {
            uint2 vv;
            vv.x = (unsigned)f2bf(acc[i][0]) | ((unsigned)f2bf(acc[i][1]) << 16);
            vv.y = (unsigned)f2bf(acc[i][2]) | ((unsigned)f2bf(acc[i][3]) << 16);
            *(uint2*)&sm[PT_E + cc * 264 + nb] = vv;
        }
    }
}

// ---------------------------------------------------------------------------
__global__ __launch_bounds__(1024, 4) void fused(const float* __restrict__ X,
                                                 const unsigned short* __restrict__ ws,
                                                 float* __restrict__ out)
{
    __shared__ unsigned short sm[68872];          // 137,744 B
    float* outS = (float*)sm;                     // stride 132 floats, overlays PT

    const int t  = threadIdx.x;
    const int w  = t >> 6;
    const int ln = t & 15;
    const int q  = (t & 63) >> 4;
    const float* __restrict__ Xi = X + (size_t)blockIdx.x * 65536;

    const unsigned short* __restrict__ W1 = ws;
    const unsigned short* __restrict__ W2 = ws + 36864;
    const unsigned short* __restrict__ W3 = ws + 102400;
    const unsigned short* __restrict__ W4 = ws + 118784;

    // ---- stage panel 0 (coalesced: 64 lanes = one full 1KB row) ----
    float4 r0[8], r1[8];
#pragma unroll
    for (int i = 0; i < 8; ++i) r0[i] = ((const float4*)Xi)[i * 1024 + t];
#pragma unroll
    for (int i = 0; i < 8; ++i) {
        const int f = i * 1024 + t;
        const int n = f >> 6, m = (f & 63) * 4;
        *(uint2*)&sm[XB_E + n * 264 + m] = pack4(r0[i]);
    }
    __syncthreads();

    // prefetch panel 1 into registers (overlaps phase A on panel 0)
#pragma unroll
    for (int i = 0; i < 8; ++i) r1[i] = ((const float4*)(Xi + 32768))[i * 1024 + t];

    phaseA(sm, W1, 0, w, ln, q);
    __syncthreads();

#pragma unroll
    for (int i = 0; i < 8; ++i) {
        const int f = i * 1024 + t;
        const int n = f >> 6, m = (f & 63) * 4;
        *(uint2*)&sm[XB_E + n * 264 + m] = pack4(r1[i]);
    }
    __syncthreads();

    phaseA(sm, W1, 1, w, ln, q);
    __syncthreads();

    // ---- Phase B: Dc[u][v] = sum_k W2[u][k] * Pt[row(v,k)][col(k)] ----
    {
        const int u0 = (w & 7) * 16;
        const int vh = w >> 3;
        ffrag acc[4];
#pragma unroll
        for (int i = 0; i < 4; ++i) acc[i] = (ffrag){0.f, 0.f, 0.f, 0.f};

#pragma unroll
        for (int kk = 0; kk < 16; ++kk) {
            const int k = kk * 32 + q * 8;
            const bfrag A = *(const bfrag*)(W2 + (size_t)(u0 + ln) * 512 + k);
            const bool loK = (kk < 8);
#pragma unroll
            for (int i = 0; i < 4; ++i) {
                const int v   = (vh * 4 + i) * 16 + ln;
                const int row = loK ? v : (128 - v);
                const int col = loK ? k : (k - 256);
                const bfrag B = *(const bfrag*)&sm[PT_E + row * 264 + col];
                acc[i] = __builtin_amdgcn_mfma_f32_16x16x32_bf16(A, B, acc[i], 0, 0, 0);
            }
        }
        // store Dc bf16 into LDS (Xb is dead)
#pragma unroll
        for (int i = 0; i < 4; ++i) {
            const int v = (vh * 4 + i) * 16 + ln;
#pragma unroll
            for (int r = 0; r < 4; ++r)
                sm[DCB_E + (u0 + 4 * q + r) * 136 + v] = f2bf(acc[i][r]);
        }
    }
    __syncthreads();

    // ---- Phase A2: P2t[c][p] = sum_m Dcb[p][m] * W3t[c][m] ----
    {
        const int p0  = (w & 7) * 16;
        const int ct0 = (w >> 3) * 4;
        ffrag acc[4];
#pragma unroll
        for (int i = 0; i < 4; ++i) acc[i] = (ffrag){0.f, 0.f, 0.f, 0.f};

#pragma unroll
        for (int kk = 0; kk < 4; ++kk) {
            const int k = kk * 32 + q * 8;
            const bfrag A = *(const bfrag*)&sm[DCB_E + (p0 + ln) * 136 + k];
#pragma unroll
            for (int i = 0; i < 4; ++i) {
                const bfrag B = *(const bfrag*)(W3 + ((ct0 + i) * 16 + ln) * 128 + k);
                acc[i] = __builtin_amdgcn_mfma_f32_16x16x32_bf16(A, B, acc[i], 0, 0, 0);
            }
        }
#pragma unroll
        for (int i = 0; i < 4; ++i) {
            const int cc = (ct0 + i) * 16 + ln;
            uint2 vv;
            vv.x = (unsigned)f2bf(acc[i][0]) | ((unsigned)f2bf(acc[i][1]) << 16);
            vv.y = (unsigned)f2bf(acc[i][2]) | ((unsigned)f2bf(acc[i][3]) << 16);
            *(uint2*)&sm[P2T_E + cc * 136 + p0 + 4 * q] = vv;
        }
    }
    __syncthreads();

    // ---- Phase B2: out[u][v] = sum_k W4[u][k] * P2x[row(v,k)][col(k)] ----
    {
        const int u0 = (w & 7) * 16;
        const int vh = w >> 3;
        ffrag o[4];
#pragma unroll
        for (int i = 0; i < 4; ++i) o[i] = (ffrag){0.f, 0.f, 0.f, 0.f};

#pragma unroll
        for (int kk = 0; kk < 8; ++kk) {
            const int k = kk * 32 + q * 8;
            const bfrag A = *(const bfrag*)(W4 + (size_t)(u0 + ln) * 256 + k);
            const bool loK = (kk < 4);
#pragma unroll
            for (int i = 0; i < 4; ++i) {
                const int v   = (vh * 4 + i) * 16 + ln;
                const int row = loK ? v : ((128 - v) & 127);
                const int col = loK ? k : (k - 128);
                const bfrag B = *(const bfrag*)&sm[P2T_E + row * 136 + col];
                o[i] = __builtin_amdgcn_mfma_f32_16x16x32_bf16(A, B, o[i], 0, 0, 0);
            }
        }
        // stage fp32 result in LDS (PT region is dead) for coalesced store
#pragma unroll
        for (int i = 0; i < 4; ++i) {
            const int v = (vh * 4 + i) * 16 + ln;
#pragma unroll
            for (int r = 0; r < 4; ++r)
                outS[(u0 + 4 * q + r) * 132 + v] = o[i][r];
        }
    }
    __syncthreads();

    // ---- coalesced output copy ----
    {
        float* __restrict__ G = out + (size_t)blockIdx.x * 16384;
#pragma unroll
        for (int i = 0; i < 4; ++i) {
            const int f  = i * 1024 + t;     // float4 index
            const int u  = f >> 5, v4 = f & 31;
            const float4 val = *(const float4*)&outS[u * 132 + v4 * 4];
            *(float4*)&G[u * 128 + v4 * 4] = val;
        }
    }
}

// ---------------------------------------------------------------------------
extern "C" void kernel_launch(void* const* d_in, const int* in_sizes, int n_in,
                              void* d_out, int out_size, void* d_ws, size_t ws_size,
                              hipStream_t stream)
{
    const float* x = (const float*)d_in[0];
    float* out = (float*)d_out;
    unsigned short* tw = (unsigned short*)d_ws;   // needs 303,104 bytes

    gen_tables<<<dim3(256), dim3(256), 0, stream>>>(tw);
    fused<<<dim3(512), dim3(1024), 0, stream>>>(x, tw, out);
}